// Round 7
// baseline (169.807 us; speedup 1.0000x reference)
//
#include <hip/hip_runtime.h>
#include <hip/hip_bf16.h>

#define F 1024
#define B_ROWS 16384

typedef short v8s __attribute__((ext_vector_type(8)));
typedef float v4f __attribute__((ext_vector_type(4)));
typedef unsigned short v8u __attribute__((ext_vector_type(8)));
typedef unsigned short ushort_t;

__device__ __forceinline__ unsigned short f2bf(float f) {
    unsigned int u = __builtin_bit_cast(unsigned int, f);
    u = (u + 0x7FFFu + ((u >> 16) & 1u)) >> 16;  // RNE
    return (unsigned short)u;
}

// async global->LDS, 16B per lane. LDS dest = wave-uniform base + lane*16.
__device__ __forceinline__ void gload_lds16(const ushort_t* g, ushort_t* l) {
    __builtin_amdgcn_global_load_lds(
        (const __attribute__((address_space(1))) unsigned int*)g,
        (__attribute__((address_space(3))) unsigned int*)l,
        16, 0, 0);
}

// B chunk layout: chunk (rb, cb) = 16-row x 32-col bf16 block, stored
// [lane][8 bf16] in MFMA operand order: lane l -> row rb*16 + (l&15),
// cols cb*32 + (l>>4)*8 .. +8. One chunk = 1 KB.
// B is the STRICTLY UPPER-TRIANGULAR W (value at (n,k) = w_{kn} for k<n
// else 0). GEMM for N-tile nt only needs K < 128*(nt+1): 56% of the MACs.
//
// POISON LOG (r11-r15, keep forever):
//  - fused-sigmoid epilogue in gemm (threadfence + agent-scope acq_rel
//    counter + extra args): CONVICTED by controlled revert -- perturbs
//    main-loop codegen (MfmaUtil 20->4.4%, gemm 40->170us). Separate kernel.
//  - __launch_bounds__(256,4): unified VGPR+AGPR cap 128 < needed -> spill.
//  - ring-3 + no-drain barrier (r16): correct but NEUTRAL. Keep the simple
//    2-buffer __syncthreads() loop; compiler + 3-block TLP already covers it.
//
// r17: X-pack pass ELIMINATED. The gemm builds A-fragments directly from
// fp32 x (2x float4 per fragment + scalar bf16 casts; compiler fuses pairs
// into v_cvt_pk_bf16_f32). Identical RNE numerics; prep is now just
// acc-zero + 2MB B-pack. Saves the 96MB X-pack pass (~15-35us of prep).

// prep: [0,64) zero rowacc; [64,576) pack triangular B.
__global__ __launch_bounds__(256) void prep_kernel(
        const float* __restrict__ w,
        ushort_t* __restrict__ Bp,
        float* __restrict__ acc) {
    const int bid  = blockIdx.x;
    const int tid  = threadIdx.x;
    const int lane = tid & 63;
    const int wave = tid >> 6;
    const int l16  = lane & 15;
    const int quad = lane >> 4;

    if (bid < 64) {
        acc[bid * 256 + tid] = 0.0f;
    } else {
        const int c  = (bid - 64) * 4 + wave;    // 0..2047
        const int n  = (c >> 5) * 16 + l16;      // output-col axis
        const int k0 = (c & 31) * 32 + quad * 8; // contraction axis
        v8u o;
#pragma unroll
        for (int e = 0; e < 8; ++e) {
            const int k = k0 + e;
            float v = 0.0f;
            if (k < n) {  // strictly upper: pair (k,n), k<n
                const int idx = k * (F - 1) - (k * (k - 1)) / 2 + (n - k - 1);
                v = w[idx];  // scattered read; w = 2MB, L2-resident
            }
            o[e] = f2bf(v);
        }
        *(v8u*)(Bp + (size_t)c * 512 + lane * 8) = o;
    }
}

// Hybrid GEMM, triangular-K (r1 2-buffer schedule): A fragments built
// directly from fp32 X (load + cvt_pk to bf16, ping-pong, compiler-
// scheduled), B multicast through LDS, double-buffered 16KB chunks, next
// chunk's staging issued right after the barrier that opens the current
// one. Plain __syncthreads() per chunk.
__global__ __launch_bounds__(256, 3) void gemm_kernel(
        const ushort_t* __restrict__ Bp,   // packed triangular-W chunks
        const float*   __restrict__ X,     // fp32 X (A operand + epilogue)
        float*         __restrict__ rowacc) {
    __shared__ ushort_t Bs[2 * 16 * 512];  // 2 bufs x (2 kg x 8 ng) x 1KB = 32 KB

    const int f   = blockIdx.x;          // 0..1023
    const int xcd = f & 7;
    const int g   = f >> 3;              // 0..127
    const int y   = g & 15;
    const int nt  = 7 - (g >> 4);        // heavy (nt=7, 16 chunks) first
    const int blockM = (xcd * 16 + y) * 128;
    const int blockN = nt * 128;
    const int nch    = 2 * (nt + 1);     // K-chunks of 64 needed: K < 128*(nt+1)

    const int tid   = threadIdx.x;
    const int lane  = tid & 63;
    const int wave  = tid >> 6;
    const int waveM = wave >> 1;
    const int waveN = wave & 1;
    const int quad  = lane >> 4;
    const int l16   = lane & 15;

    // A-fragment geometry (16x16x32 A operand): lane l -> row l&15,
    // k-cols (l>>4)*8..+8 of the 16x32 subtile.
    const int aRow = blockM + waveM * 64 + l16;
    const int aCol = quad * 8;
    const float* Arow = X + (size_t)aRow * F + aCol;

    // B staging: each wave stages 4 of the 16 1KB-frag-chunks per 16KB chunk
    const int q0   = wave * 4;
    const int ngB  = nt * 8;

#define STAGE_B(c, buf)                                                        \
    {                                                                          \
        _Pragma("unroll")                                                      \
        for (int q = 0; q < 4; ++q) {                                          \
            const int qq  = q0 + q;                                            \
            const int kgl = qq >> 3, ngl = qq & 7;                             \
            gload_lds16(Bp + (size_t)((ngB + ngl) * 32 + (c) * 2 + kgl) * 512 + lane * 8, \
                        Bs + (buf) * 8192 + (kgl * 8 + ngl) * 512);            \
        }                                                                      \
    }

    // Load A fragments for k-group t (32 cols): 2x float4 + 8 bf16 casts.
#define LOAD_A(dst, t)                                                         \
    {                                                                          \
        _Pragma("unroll")                                                      \
        for (int mi = 0; mi < 4; ++mi) {                                       \
            const float* src = Arow + (size_t)(mi * 16) * F + (t) * 32;        \
            float4 v0 = *(const float4*)(src);                                 \
            float4 v1 = *(const float4*)(src + 4);                             \
            v8u o;                                                             \
            o[0] = f2bf(v0.x); o[1] = f2bf(v0.y);                              \
            o[2] = f2bf(v0.z); o[3] = f2bf(v0.w);                              \
            o[4] = f2bf(v1.x); o[5] = f2bf(v1.y);                              \
            o[6] = f2bf(v1.z); o[7] = f2bf(v1.w);                              \
            dst[mi] = (v8s)o;                                                  \
        }                                                                      \
    }

    v4f acc[4][4];
#pragma unroll
    for (int i = 0; i < 4; i++)
#pragma unroll
        for (int j = 0; j < 4; j++) acc[i][j] = (v4f)(0.0f);

    v8s a0[4], a1[4], bfr[4];

    // prologue: stage chunk 0, prefetch A t=0
    STAGE_B(0, 0)
    LOAD_A(a0, 0)
    __syncthreads();  // chunk 0 staged

    for (int c = 0; c < nch; ++c) {
        const int  buf  = c & 1;
        const bool more = (c + 1 < nch);
        if (more) STAGE_B(c + 1, buf ^ 1)  // in flight across this chunk

        // ---- t = 2c (even kg of chunk) ----
#pragma unroll
        for (int ni = 0; ni < 4; ++ni)
            bfr[ni] = *(const v8s*)(Bs + buf * 8192 + (0 * 8 + waveN * 4 + ni) * 512 + lane * 8);
        LOAD_A(a1, 2 * c + 1)
#pragma unroll
        for (int mi = 0; mi < 4; ++mi)
#pragma unroll
            for (int ni = 0; ni < 4; ++ni)
                acc[mi][ni] = __builtin_amdgcn_mfma_f32_16x16x32_bf16(
                    a0[mi], bfr[ni], acc[mi][ni], 0, 0, 0);

        // ---- t = 2c+1 (odd kg of chunk) ----
#pragma unroll
        for (int ni = 0; ni < 4; ++ni)
            bfr[ni] = *(const v8s*)(Bs + buf * 8192 + (1 * 8 + waveN * 4 + ni) * 512 + lane * 8);
        if (more) LOAD_A(a0, 2 * c + 2)
#pragma unroll
        for (int mi = 0; mi < 4; ++mi)
#pragma unroll
            for (int ni = 0; ni < 4; ++ni)
                acc[mi][ni] = __builtin_amdgcn_mfma_f32_16x16x32_bf16(
                    a1[mi], bfr[ni], acc[mi][ni], 0, 0, 0);

        if (more) __syncthreads();  // gates buffer reuse; staging c+1 landed
    }
#undef STAGE_B
#undef LOAD_A

    // Epilogue: C/D mapping (verified): col = lane&15, row = quad*4 + reg.
#pragma unroll
    for (int mi = 0; mi < 4; mi++) {
#pragma unroll
        for (int r = 0; r < 4; r++) {
            const int b = blockM + waveM * 64 + mi * 16 + quad * 4 + r;
            const float* xr = X + (size_t)b * F + blockN + waveN * 64 + l16;
            float pv = acc[mi][0][r] * xr[0]
                     + acc[mi][1][r] * xr[16]
                     + acc[mi][2][r] * xr[32]
                     + acc[mi][3][r] * xr[48];
            pv += __shfl_xor(pv, 1);
            pv += __shfl_xor(pv, 2);
            pv += __shfl_xor(pv, 4);
            pv += __shfl_xor(pv, 8);
            if (l16 == 0) atomicAdd(&rowacc[b], pv);
        }
    }
}

__global__ void sigmoid_kernel(const float* __restrict__ acc, float* __restrict__ out) {
    int b = blockIdx.x * blockDim.x + threadIdx.x;
    out[b] = 1.0f / (1.0f + __expf(-acc[b]));
}

// Correctness fallback if workspace is too small: direct per-row computation.
__global__ void fallback_kernel(const float* __restrict__ x, const float* __restrict__ w,
                                float* __restrict__ out) {
    __shared__ float xs[F];
    __shared__ float partial[4];
    const int b = blockIdx.x;
    for (int i = threadIdx.x; i < F; i += 256) xs[i] = x[(size_t)b * F + i];
    __syncthreads();
    float s = 0.0f;
    for (int i = threadIdx.x; i < F - 1; i += 256) {
        const float xi = xs[i];
        const int kbase = i * (F - 1) - (i * (i - 1)) / 2 - i - 1;
        for (int j = i + 1; j < F; j++) s += w[kbase + j] * xi * xs[j];
    }
    for (int off = 32; off; off >>= 1) s += __shfl_down(s, off);
    if ((threadIdx.x & 63) == 0) partial[threadIdx.x >> 6] = s;
    __syncthreads();
    if (threadIdx.x == 0) {
        float t = partial[0] + partial[1] + partial[2] + partial[3];
        out[b] = 1.0f / (1.0f + __expf(-t));
    }
}

extern "C" void kernel_launch(void* const* d_in, const int* in_sizes, int n_in,
                              void* d_out, int out_size, void* d_ws, size_t ws_size,
                              hipStream_t stream) {
    const float* x = (const float*)d_in[0];
    const float* w = (const float*)d_in[1];
    float* out = (float*)d_out;

    const size_t acc_bytes = 65536;                       // 16384 fp32 (rounded)
    const size_t B_bytes   = (size_t)F * F * 2;           // 2 MiB packed triangular W
    const size_t needed = acc_bytes + B_bytes;

    if (ws_size < needed) {
        fallback_kernel<<<B_ROWS, 256, 0, stream>>>(x, w, out);
        return;
    }

    float*    acc = (float*)d_ws;
    ushort_t* Bp  = (ushort_t*)((char*)d_ws + acc_bytes);

    // prep: 64 (acc zero) + 512 (pack B)  -- no X-pack pass anymore
    prep_kernel<<<64 + 512, 256, 0, stream>>>(w, Bp, acc);
    // 128 M-tiles x 8 N-tiles; per-block K-extent 2*(nt+1) chunks (triangular)
    gemm_kernel<<<1024, 256, 0, stream>>>(Bp, x, acc);
    sigmoid_kernel<<<B_ROWS / 256, 256, 0, stream>>>(acc, out);
}

// Round 8
// 136.008 us; speedup vs baseline: 1.2485x; 1.2485x over previous
//
#include <hip/hip_runtime.h>
#include <hip/hip_bf16.h>

#define F 1024
#define B_ROWS 16384

typedef short v8s __attribute__((ext_vector_type(8)));
typedef float v4f __attribute__((ext_vector_type(4)));
typedef unsigned short v8u __attribute__((ext_vector_type(8)));
typedef unsigned short ushort_t;

__device__ __forceinline__ unsigned short f2bf(float f) {
    unsigned int u = __builtin_bit_cast(unsigned int, f);
    u = (u + 0x7FFFu + ((u >> 16) & 1u)) >> 16;  // RNE
    return (unsigned short)u;
}

// async global->LDS, 16B per lane. LDS dest = wave-uniform base + lane*16.
__device__ __forceinline__ void gload_lds16(const ushort_t* g, ushort_t* l) {
    __builtin_amdgcn_global_load_lds(
        (const __attribute__((address_space(1))) unsigned int*)g,
        (__attribute__((address_space(3))) unsigned int*)l,
        16, 0, 0);
}

// Chunk (rb, cb) = 16-row x 32-col bf16 block stored [lane][8 bf16] in MFMA
// operand order: lane l -> row rb*16 + (l&15), cols cb*32 + (l>>4)*8..+8.
// One chunk = 1 KB. B = strictly upper-triangular W ((n,k) = w_{kn}, k<n).
// N-tile nt needs K < 128*(nt+1): 56% of the full-GEMM MACs.
//
// POISON LOG (r11-r17, keep forever):
//  - fused-sigmoid epilogue in gemm (agent-scope atomics/fence in-kernel):
//    CONVICTED -- perturbs main-loop codegen (MfmaUtil 20->4.4%). Separate.
//  - __launch_bounds__(256,4): unified VGPR+AGPR cap 128 < 136 -> spill.
//  - ring-3 + no-drain barrier (r16): correct but NEUTRAL. Keep 2-buffer
//    __syncthreads() loop.
//  - X-pack fused into gemm (r17): FAILED 38->94us. Re-converts each X
//    element ~4.5x and puts 8 fp32 loads + 32 cvts on the MFMA critical
//    path. Conversion stays amortized in prep; gemm operands stay bf16.
//
// r18: K-split job decomposition for balance. nt>=4 tiles split into two
// K-half jobs -> 12 jobs/M-tile, sizes {8,8,8,7,6,7,5,6,5,6,4,2} (sum 72),
// interleaved so even/odd dispatch positions each sum 36 chunk-units/CU
// (was 40/32 with whole tiles). Grid 1536 = 6 jobs/CU. Epilogue atomicAdd
// already accumulates across K-splits -- no other change.

// prep: [0,64) zero rowacc; [64,576) pack triangular B; [576,8768) pack X.
__global__ __launch_bounds__(256) void prep_kernel(
        const float* __restrict__ w, const float* __restrict__ x,
        ushort_t* __restrict__ Bp, ushort_t* __restrict__ Xp,
        float* __restrict__ acc) {
    const int bid  = blockIdx.x;
    const int tid  = threadIdx.x;
    const int lane = tid & 63;
    const int wave = tid >> 6;
    const int l16  = lane & 15;
    const int quad = lane >> 4;

    if (bid < 64) {
        acc[bid * 256 + tid] = 0.0f;
    } else if (bid < 576) {
        const int c  = (bid - 64) * 4 + wave;    // 0..2047
        const int n  = (c >> 5) * 16 + l16;      // output-col axis
        const int k0 = (c & 31) * 32 + quad * 8; // contraction axis
        v8u o;
#pragma unroll
        for (int e = 0; e < 8; ++e) {
            const int k = k0 + e;
            float v = 0.0f;
            if (k < n) {  // strictly upper: pair (k,n), k<n
                const int idx = k * (F - 1) - (k * (k - 1)) / 2 + (n - k - 1);
                v = w[idx];  // scattered read; w = 2MB, L2-resident
            }
            o[e] = f2bf(v);
        }
        *(v8u*)(Bp + (size_t)c * 512 + lane * 8) = o;
    } else {
        const int c  = (bid - 576) * 4 + wave;  // 0..32767
        const int r  = (c >> 5) * 16 + l16;     // X row
        const int k0 = (c & 31) * 32 + quad * 8;
        const float* src = x + (size_t)r * F + k0;
        float4 v0 = *(const float4*)(src);
        float4 v1 = *(const float4*)(src + 4);
        v8u o;
        o[0] = f2bf(v0.x); o[1] = f2bf(v0.y); o[2] = f2bf(v0.z); o[3] = f2bf(v0.w);
        o[4] = f2bf(v1.x); o[5] = f2bf(v1.y); o[6] = f2bf(v1.z); o[7] = f2bf(v1.w);
        *(v8u*)(Xp + (size_t)c * 512 + lane * 8) = o;
    }
}

// Job tables, 4-bit fields indexed by j = 0..11 (nibble j of the constant):
//   j  : 0  1  2  3  4  5  6  7  8  9 10 11
//   nt : 7  3  7  6  5  6  4  5  4  2  1  0
//   c0 : 0  0  8  0  0  7  0  6  5  0  0  0
//   nc : 8  8  8  7  6  7  5  6  5  6  4  2
// Even dispatch positions sum 36, odd sum 36 -> balanced CU queues.
#define NT_TBL 0x012454656737ULL
#define C0_TBL 0x000560700800ULL
#define NC_TBL 0x246565767888ULL

// Hybrid GEMM, triangular-K, K-split jobs (r18; r5 inner loop unchanged):
// A fragments direct global->VGPR (ping-pong, compiler-scheduled), B
// multicast through LDS, double-buffered 16KB chunks, plain __syncthreads().
__global__ __launch_bounds__(256, 3) void gemm_kernel(
        const ushort_t* __restrict__ Xp,   // packed X chunks
        const ushort_t* __restrict__ Bp,   // packed triangular-W chunks
        const float*   __restrict__ Xf,    // fp32 X (epilogue)
        float*         __restrict__ rowacc) {
    __shared__ ushort_t Bs[2 * 16 * 512];  // 2 bufs x (2 kg x 8 ng) x 1KB = 32 KB

    const int f   = blockIdx.x;          // 0..1535
    const int xcd = f & 7;
    const int r   = f >> 3;              // 0..191
    const int y   = r & 15;
    const int j   = r >> 4;              // job id 0..11
    const int nt  = (int)((NT_TBL >> (4 * j)) & 15);
    const int c0  = (int)((C0_TBL >> (4 * j)) & 15);
    const int nc  = (int)((NC_TBL >> (4 * j)) & 15);
    const int blockM = (xcd * 16 + y) * 128;
    const int blockN = nt * 128;
    const int cEnd   = c0 + nc;

    const int tid   = threadIdx.x;
    const int lane  = tid & 63;
    const int wave  = tid >> 6;
    const int waveM = wave >> 1;
    const int waveN = wave & 1;
    const int quad  = lane >> 4;
    const int l16   = lane & 15;

    const int mg = (blockM >> 4) + waveM * 4;  // + mi
    const v8s* A8 = (const v8s*)Xp + (size_t)mg * 32 * 64 + lane;

    // B staging: each wave stages 4 of the 16 1KB-frag-chunks per 16KB chunk
    const int q0   = wave * 4;
    const int ngB  = nt * 8;

#define STAGE_B(c, buf)                                                        \
    {                                                                          \
        _Pragma("unroll")                                                      \
        for (int q = 0; q < 4; ++q) {                                          \
            const int qq  = q0 + q;                                            \
            const int kgl = qq >> 3, ngl = qq & 7;                             \
            gload_lds16(Bp + (size_t)((ngB + ngl) * 32 + (c) * 2 + kgl) * 512 + lane * 8, \
                        Bs + (buf) * 8192 + (kgl * 8 + ngl) * 512);            \
        }                                                                      \
    }

    v4f acc[4][4];
#pragma unroll
    for (int i = 0; i < 4; i++)
#pragma unroll
        for (int j2 = 0; j2 < 4; j2++) acc[i][j2] = (v4f)(0.0f);

    v8s a0[4], a1[4], bfr[4];

    // prologue: stage chunk c0, prefetch A t=2*c0
    STAGE_B(c0, 0)
#pragma unroll
    for (int mi = 0; mi < 4; ++mi) a0[mi] = A8[(mi * 32 + 2 * c0) * 64];
    __syncthreads();  // chunk c0 staged (drains a0 too; prologue only)

    for (int c = c0; c < cEnd; ++c) {
        const int  buf  = (c - c0) & 1;
        const bool more = (c + 1 < cEnd);
        if (more) STAGE_B(c + 1, buf ^ 1)  // in flight across this chunk

        // ---- t = 2c (even kg of chunk) ----
#pragma unroll
        for (int ni = 0; ni < 4; ++ni)
            bfr[ni] = *(const v8s*)(Bs + buf * 8192 + (0 * 8 + waveN * 4 + ni) * 512 + lane * 8);
#pragma unroll
        for (int mi = 0; mi < 4; ++mi) a1[mi] = A8[(mi * 32 + 2 * c + 1) * 64];
#pragma unroll
        for (int mi = 0; mi < 4; ++mi)
#pragma unroll
            for (int ni = 0; ni < 4; ++ni)
                acc[mi][ni] = __builtin_amdgcn_mfma_f32_16x16x32_bf16(
                    a0[mi], bfr[ni], acc[mi][ni], 0, 0, 0);

        // ---- t = 2c+1 (odd kg of chunk) ----
#pragma unroll
        for (int ni = 0; ni < 4; ++ni)
            bfr[ni] = *(const v8s*)(Bs + buf * 8192 + (1 * 8 + waveN * 4 + ni) * 512 + lane * 8);
        if (more) {
#pragma unroll
            for (int mi = 0; mi < 4; ++mi) a0[mi] = A8[(mi * 32 + 2 * c + 2) * 64];
        }
#pragma unroll
        for (int mi = 0; mi < 4; ++mi)
#pragma unroll
            for (int ni = 0; ni < 4; ++ni)
                acc[mi][ni] = __builtin_amdgcn_mfma_f32_16x16x32_bf16(
                    a1[mi], bfr[ni], acc[mi][ni], 0, 0, 0);

        if (more) __syncthreads();  // gates buffer reuse; staging c+1 landed
    }
#undef STAGE_B

    // Epilogue: C/D mapping (verified): col = lane&15, row = quad*4 + reg.
    // atomicAdd accumulates across the K-split jobs of the same (M,N) tile.
#pragma unroll
    for (int mi = 0; mi < 4; mi++) {
#pragma unroll
        for (int rr = 0; rr < 4; rr++) {
            const int b = blockM + waveM * 64 + mi * 16 + quad * 4 + rr;
            const float* xr = Xf + (size_t)b * F + blockN + waveN * 64 + l16;
            float pv = acc[mi][0][rr] * xr[0]
                     + acc[mi][1][rr] * xr[16]
                     + acc[mi][2][rr] * xr[32]
                     + acc[mi][3][rr] * xr[48];
            pv += __shfl_xor(pv, 1);
            pv += __shfl_xor(pv, 2);
            pv += __shfl_xor(pv, 4);
            pv += __shfl_xor(pv, 8);
            if (l16 == 0) atomicAdd(&rowacc[b], pv);
        }
    }
}

__global__ void sigmoid_kernel(const float* __restrict__ acc, float* __restrict__ out) {
    int b = blockIdx.x * blockDim.x + threadIdx.x;
    out[b] = 1.0f / (1.0f + __expf(-acc[b]));
}

// Correctness fallback if workspace is too small: direct per-row computation.
__global__ void fallback_kernel(const float* __restrict__ x, const float* __restrict__ w,
                                float* __restrict__ out) {
    __shared__ float xs[F];
    __shared__ float partial[4];
    const int b = blockIdx.x;
    for (int i = threadIdx.x; i < F; i += 256) xs[i] = x[(size_t)b * F + i];
    __syncthreads();
    float s = 0.0f;
    for (int i = threadIdx.x; i < F - 1; i += 256) {
        const float xi = xs[i];
        const int kbase = i * (F - 1) - (i * (i - 1)) / 2 - i - 1;
        for (int j = i + 1; j < F; j++) s += w[kbase + j] * xi * xs[j];
    }
    for (int off = 32; off; off >>= 1) s += __shfl_down(s, off);
    if ((threadIdx.x & 63) == 0) partial[threadIdx.x >> 6] = s;
    __syncthreads();
    if (threadIdx.x == 0) {
        float t = partial[0] + partial[1] + partial[2] + partial[3];
        out[b] = 1.0f / (1.0f + __expf(-t));
    }
}

extern "C" void kernel_launch(void* const* d_in, const int* in_sizes, int n_in,
                              void* d_out, int out_size, void* d_ws, size_t ws_size,
                              hipStream_t stream) {
    const float* x = (const float*)d_in[0];
    const float* w = (const float*)d_in[1];
    float* out = (float*)d_out;

    const size_t acc_bytes = 65536;                       // 16384 fp32 (rounded)
    const size_t B_bytes   = (size_t)F * F * 2;           // 2 MiB packed triangular W
    const size_t Xp_bytes  = (size_t)B_ROWS * F * 2;      // 32 MiB packed X
    const size_t needed = acc_bytes + B_bytes + Xp_bytes;

    if (ws_size < needed) {
        fallback_kernel<<<B_ROWS, 256, 0, stream>>>(x, w, out);
        return;
    }

    float*    acc = (float*)d_ws;
    ushort_t* Bp  = (ushort_t*)((char*)d_ws + acc_bytes);
    ushort_t* Xp  = (ushort_t*)((char*)d_ws + acc_bytes + B_bytes);

    // prep: 64 (acc zero) + 512 (pack B) + 8192 (pack X)
    prep_kernel<<<64 + 512 + 8192, 256, 0, stream>>>(w, x, Bp, Xp, acc);
    // 128 M-tiles x 12 balanced K-split jobs (see tables above)
    gemm_kernel<<<1536, 256, 0, stream>>>(Xp, Bp, x, acc);
    sigmoid_kernel<<<B_ROWS / 256, 256, 0, stream>>>(acc, out);
}

// Round 9
// 128.639 us; speedup vs baseline: 1.3200x; 1.0573x over previous
//
#include <hip/hip_runtime.h>
#include <hip/hip_bf16.h>

#define F 1024
#define B_ROWS 16384

typedef short v8s __attribute__((ext_vector_type(8)));
typedef float v4f __attribute__((ext_vector_type(4)));
typedef unsigned short v8u __attribute__((ext_vector_type(8)));
typedef unsigned short ushort_t;

__device__ __forceinline__ unsigned short f2bf(float f) {
    unsigned int u = __builtin_bit_cast(unsigned int, f);
    u = (u + 0x7FFFu + ((u >> 16) & 1u)) >> 16;  // RNE
    return (unsigned short)u;
}

// async global->LDS, 16B per lane. LDS dest = wave-uniform base + lane*16.
__device__ __forceinline__ void gload_lds16(const ushort_t* g, ushort_t* l) {
    __builtin_amdgcn_global_load_lds(
        (const __attribute__((address_space(1))) unsigned int*)g,
        (__attribute__((address_space(3))) unsigned int*)l,
        16, 0, 0);
}

// Chunk (rb, cb) = 16-row x 32-col bf16 block stored [lane][8 bf16] in MFMA
// operand order: lane l -> row rb*16 + (l&15), cols cb*32 + (l>>4)*8..+8.
// One chunk = 1 KB. B = strictly upper-triangular W ((n,k) = w_{kn}, k<n).
// N-tile nt needs K < 128*(nt+1): 56% of the full-GEMM MACs.
//
// POISON LOG (r11-r18, keep forever):
//  - fused-sigmoid epilogue in gemm (agent-scope atomics/fence in-kernel):
//    CONVICTED -- perturbs main-loop codegen (MfmaUtil 20->4.4%). Separate.
//  - __launch_bounds__(256,4): unified VGPR+AGPR cap 128 < needed -> spill.
//  - ring-3 + no-drain barrier (r16): correct but NEUTRAL.
//  - X-pack fused into gemm (r17): FAILED 38->94us (re-converts X ~4.5x,
//    fp32 loads + cvts on MFMA critical path). Conversion stays in prep.
//  - K-split jobs (r18): REGRESSION 39->44.5us gemm (extra prologues/
//    epilogues + A-panel re-reads; balance was not the constraint).
//
// r19: m97-structure gemm. Previous loop kept A as per-wave global->VGPR
// ping-pong: 8 global loads per barrier with ~160cyc of MFMA cover against
// 200-900cyc L2/HBM latency, and 2x duplicate A fetches (waveM pairs).
// Now BOTH operands stage through LDS via global_load_lds (the guide's
// verified 874-TF structure): K-step=32, per step 8 A-chunks + 8 B-chunks
// (16KB), waves 0-1 stage A, waves 2-3 stage B, 4+4 ds_read_b128 + 16 MFMA
// + 1 barrier per wave per step. Zero per-wave global loads in the loop.

// prep: [0,64) zero rowacc; [64,576) pack triangular B; [576,8768) pack X.
__global__ __launch_bounds__(256) void prep_kernel(
        const float* __restrict__ w, const float* __restrict__ x,
        ushort_t* __restrict__ Bp, ushort_t* __restrict__ Xp,
        float* __restrict__ acc) {
    const int bid  = blockIdx.x;
    const int tid  = threadIdx.x;
    const int lane = tid & 63;
    const int wave = tid >> 6;
    const int l16  = lane & 15;
    const int quad = lane >> 4;

    if (bid < 64) {
        acc[bid * 256 + tid] = 0.0f;
    } else if (bid < 576) {
        const int c  = (bid - 64) * 4 + wave;    // 0..2047
        const int n  = (c >> 5) * 16 + l16;      // output-col axis
        const int k0 = (c & 31) * 32 + quad * 8; // contraction axis
        v8u o;
#pragma unroll
        for (int e = 0; e < 8; ++e) {
            const int k = k0 + e;
            float v = 0.0f;
            if (k < n) {  // strictly upper: pair (k,n), k<n
                const int idx = k * (F - 1) - (k * (k - 1)) / 2 + (n - k - 1);
                v = w[idx];  // scattered read; w = 2MB, L2-resident
            }
            o[e] = f2bf(v);
        }
        *(v8u*)(Bp + (size_t)c * 512 + lane * 8) = o;
    } else {
        const int c  = (bid - 576) * 4 + wave;  // 0..32767
        const int r  = (c >> 5) * 16 + l16;     // X row
        const int k0 = (c & 31) * 32 + quad * 8;
        const float* src = x + (size_t)r * F + k0;
        float4 v0 = *(const float4*)(src);
        float4 v1 = *(const float4*)(src + 4);
        v8u o;
        o[0] = f2bf(v0.x); o[1] = f2bf(v0.y); o[2] = f2bf(v0.z); o[3] = f2bf(v0.w);
        o[4] = f2bf(v1.x); o[5] = f2bf(v1.y); o[6] = f2bf(v1.z); o[7] = f2bf(v1.w);
        *(v8u*)(Xp + (size_t)c * 512 + lane * 8) = o;
    }
}

// m97-structure GEMM, triangular-K. 128x128 block, 2x2 waves, K-step 32.
// LDS: 2 bufs x (8 A-chunks + 8 B-chunks) x 1KB = 32 KB.
__global__ __launch_bounds__(256, 3) void gemm_kernel(
        const ushort_t* __restrict__ Xp,   // packed X chunks
        const ushort_t* __restrict__ Bp,   // packed triangular-W chunks
        const float*   __restrict__ Xf,    // fp32 X (epilogue)
        float*         __restrict__ rowacc) {
    __shared__ ushort_t Ls[2 * 16 * 512];  // [buf][slot 0-7=A, 8-15=B][1KB]

    const int f   = blockIdx.x;          // 0..1023
    const int xcd = f & 7;
    const int g   = f >> 3;              // 0..127
    const int y   = g & 15;
    const int nt  = 7 - (g >> 4);        // heavy (nt=7) first
    const int blockM = (xcd * 16 + y) * 128;
    const int blockN = nt * 128;
    const int tEnd   = 4 * (nt + 1);     // K-steps of 32: K < 128*(nt+1)

    const int tid   = threadIdx.x;
    const int lane  = tid & 63;
    const int wave  = tid >> 6;
    const int waveM = wave >> 1;
    const int waveN = wave & 1;
    const int quad  = lane >> 4;
    const int l16   = lane & 15;

    const int mgBase = blockM >> 4;      // first A row-group (of 8)
    const int ngB    = nt * 8;           // first B row-group (of 8)

    // Staging: waves 0-1 stage the 8 A-chunks, waves 2-3 the 8 B-chunks.
    // Per wave 4 gload_lds16 per K-step; wave-uniform LDS dest + lane*16.
    const bool stageA = (wave < 2);
    const int  qBase  = (wave & 1) * 4;  // chunk offset within A or B half
    const ushort_t* gsrc0 = stageA
        ? Xp + ((size_t)(mgBase + qBase) * 32) * 512
        : Bp + ((size_t)(ngB  + qBase) * 32) * 512;
    const int slot0 = (stageA ? 0 : 8) + qBase;

#define STAGE(t, buf)                                                          \
    {                                                                          \
        _Pragma("unroll")                                                      \
        for (int q = 0; q < 4; ++q) {                                          \
            gload_lds16(gsrc0 + ((size_t)q * 32 + (t)) * 512 + lane * 8,       \
                        Ls + ((buf) * 16 + slot0 + q) * 512);                  \
        }                                                                      \
    }

    v4f acc[4][4];
#pragma unroll
    for (int i = 0; i < 4; i++)
#pragma unroll
        for (int j = 0; j < 4; j++) acc[i][j] = (v4f)(0.0f);

    v8s afr[4], bfr[4];

    // prologue: stage K-step 0
    STAGE(0, 0)
    __syncthreads();

    for (int t = 0; t < tEnd; ++t) {
        const int  buf  = t & 1;
        const bool more = (t + 1 < tEnd);
        if (more) STAGE(t + 1, buf ^ 1)  // in flight across this step

#pragma unroll
        for (int mi = 0; mi < 4; ++mi)
            afr[mi] = *(const v8s*)(Ls + (buf * 16 + waveM * 4 + mi) * 512 + lane * 8);
#pragma unroll
        for (int ni = 0; ni < 4; ++ni)
            bfr[ni] = *(const v8s*)(Ls + (buf * 16 + 8 + waveN * 4 + ni) * 512 + lane * 8);

#pragma unroll
        for (int mi = 0; mi < 4; ++mi)
#pragma unroll
            for (int ni = 0; ni < 4; ++ni)
                acc[mi][ni] = __builtin_amdgcn_mfma_f32_16x16x32_bf16(
                    afr[mi], bfr[ni], acc[mi][ni], 0, 0, 0);

        if (more) __syncthreads();  // gates buffer reuse; staging t+1 landed
    }
#undef STAGE

    // Epilogue: C/D mapping (verified): col = lane&15, row = quad*4 + reg.
#pragma unroll
    for (int mi = 0; mi < 4; mi++) {
#pragma unroll
        for (int r = 0; r < 4; r++) {
            const int b = blockM + waveM * 64 + mi * 16 + quad * 4 + r;
            const float* xr = Xf + (size_t)b * F + blockN + waveN * 64 + l16;
            float pv = acc[mi][0][r] * xr[0]
                     + acc[mi][1][r] * xr[16]
                     + acc[mi][2][r] * xr[32]
                     + acc[mi][3][r] * xr[48];
            pv += __shfl_xor(pv, 1);
            pv += __shfl_xor(pv, 2);
            pv += __shfl_xor(pv, 4);
            pv += __shfl_xor(pv, 8);
            if (l16 == 0) atomicAdd(&rowacc[b], pv);
        }
    }
}

__global__ void sigmoid_kernel(const float* __restrict__ acc, float* __restrict__ out) {
    int b = blockIdx.x * blockDim.x + threadIdx.x;
    out[b] = 1.0f / (1.0f + __expf(-acc[b]));
}

// Correctness fallback if workspace is too small: direct per-row computation.
__global__ void fallback_kernel(const float* __restrict__ x, const float* __restrict__ w,
                                float* __restrict__ out) {
    __shared__ float xs[F];
    __shared__ float partial[4];
    const int b = blockIdx.x;
    for (int i = threadIdx.x; i < F; i += 256) xs[i] = x[(size_t)b * F + i];
    __syncthreads();
    float s = 0.0f;
    for (int i = threadIdx.x; i < F - 1; i += 256) {
        const float xi = xs[i];
        const int kbase = i * (F - 1) - (i * (i - 1)) / 2 - i - 1;
        for (int j = i + 1; j < F; j++) s += w[kbase + j] * xi * xs[j];
    }
    for (int off = 32; off; off >>= 1) s += __shfl_down(s, off);
    if ((threadIdx.x & 63) == 0) partial[threadIdx.x >> 6] = s;
    __syncthreads();
    if (threadIdx.x == 0) {
        float t = partial[0] + partial[1] + partial[2] + partial[3];
        out[b] = 1.0f / (1.0f + __expf(-t));
    }
}

extern "C" void kernel_launch(void* const* d_in, const int* in_sizes, int n_in,
                              void* d_out, int out_size, void* d_ws, size_t ws_size,
                              hipStream_t stream) {
    const float* x = (const float*)d_in[0];
    const float* w = (const float*)d_in[1];
    float* out = (float*)d_out;

    const size_t acc_bytes = 65536;                       // 16384 fp32 (rounded)
    const size_t B_bytes   = (size_t)F * F * 2;           // 2 MiB packed triangular W
    const size_t Xp_bytes  = (size_t)B_ROWS * F * 2;      // 32 MiB packed X
    const size_t needed = acc_bytes + B_bytes + Xp_bytes;

    if (ws_size < needed) {
        fallback_kernel<<<B_ROWS, 256, 0, stream>>>(x, w, out);
        return;
    }

    float*    acc = (float*)d_ws;
    ushort_t* Bp  = (ushort_t*)((char*)d_ws + acc_bytes);
    ushort_t* Xp  = (ushort_t*)((char*)d_ws + acc_bytes + B_bytes);

    // prep: 64 (acc zero) + 512 (pack B) + 8192 (pack X)
    prep_kernel<<<64 + 512 + 8192, 256, 0, stream>>>(w, x, Bp, Xp, acc);
    // 128 M-tiles x 8 N-tiles; per-block K-extent 4*(nt+1) K-steps of 32
    gemm_kernel<<<1024, 256, 0, stream>>>(Xp, Bp, x, acc);
    sigmoid_kernel<<<B_ROWS / 256, 256, 0, stream>>>(acc, out);
}